// Round 2
// baseline (224.132 us; speedup 1.0000x reference)
//
#include <hip/hip_runtime.h>
#include <hip/hip_bf16.h>

typedef __attribute__((ext_vector_type(8))) short bf16x8;
typedef __attribute__((ext_vector_type(4))) float f32x4;

__device__ inline short f2bf(float f) {
    __hip_bfloat16 h = __float2bfloat16(f);
    short s;
    __builtin_memcpy(&s, &h, 2);
    return s;
}
__device__ inline float bf2f(short s) {
    unsigned int u = ((unsigned int)(unsigned short)s) << 16;
    float f;
    __builtin_memcpy(&f, &u, 4);
    return f;
}

// async 16B global->LDS; dest must be wave-uniform base + lane*16
__device__ inline void cp16_async(const void* g, void* l) {
    __builtin_amdgcn_global_load_lds(
        (const __attribute__((address_space(1))) void*)g,
        (__attribute__((address_space(3))) void*)l, 16, 0, 0);
}

// ---------------- prep: cast x + transpose-cast all 4 weights ----------------

__global__ void prep_kernel(const float* __restrict__ x, short* __restrict__ Xb,
                            const float* __restrict__ W0, const float* __restrict__ W1,
                            const float* __restrict__ W2, const float* __restrict__ W3,
                            short* __restrict__ W4T) {
    int bid = blockIdx.x;
    if (bid < 8192) {
        int i = bid * 256 + threadIdx.x;
        float4 f = ((const float4*)x)[i];
        union { short s[4]; int2 v; } u;
        u.s[0] = f2bf(f.x); u.s[1] = f2bf(f.y); u.s[2] = f2bf(f.z); u.s[3] = f2bf(f.w);
        ((int2*)Xb)[i] = u.v;
    } else {
        int i = (bid - 8192) * 256 + threadIdx.x;
        int w = i >> 18;
        int r = i & 262143;
        int n = r >> 9, k = r & 511;
        const float* W = (w == 0) ? W0 : (w == 1) ? W1 : (w == 2) ? W2 : W3;
        W4T[i] = f2bf(W[k * 512 + n]);
    }
}

// ========== 128x128 core, 2-phase pipelined (T3-minimum recipe, m248v2) ==========
// LDS: 2 dbufs x (A 16KB + B 16KB) = 64KB -> 2 blocks/CU at 256 threads.
// Per K-tile (BK=64): issue next tile's 8 global_load_lds, compute current,
// then ONE s_waitcnt vmcnt(0) + ONE raw s_barrier. Loads fly under the MFMA
// phase (no stage->compute drain as in the old m97-style core).
// LDS rows are 128B; XOR swizzle byte ^= (row&7)<<4 applied via pre-swizzled
// GLOBAL source (global_load_lds dest must stay linear), undone on ds_read.

#define LDS_DECL __shared__ short sm[4][8192]
// sm[0]=A buf0, sm[1]=B buf0, sm[2]=A buf1, sm[3]=B buf1

__device__ inline void stage_tile(const short* __restrict__ A, int lda,
                                  const short* __restrict__ B, int ldb, int k0,
                                  short* sA, short* sB, int tid) {
#pragma unroll
    for (int j = 0; j < 4; ++j) {
        const int L = tid * 16 + j * 4096;            // linear byte in 16KB tile
        const int row = L >> 7;                       // 128B per row (64 bf16)
        const int cb = (L & 127) ^ ((row & 7) << 4);  // inverse-swizzled src col (bytes)
        cp16_async(A + (size_t)row * lda + k0 + (cb >> 1), (char*)sA + L);
        cp16_async(B + (size_t)row * ldb + k0 + (cb >> 1), (char*)sB + L);
    }
}

__device__ inline void compute_tile(const short* sA, const short* sB, f32x4* acc,
                                    int wr, int wc, int lr, int quad) {
    const int sw = (lr & 7) << 3;                     // swizzle, short units
#pragma unroll
    for (int kk = 0; kk < 2; ++kk) {
        const int co = (kk * 32 + quad * 8) ^ sw;
        bf16x8 af[4], bfr[4];
#pragma unroll
        for (int i = 0; i < 4; ++i)
            af[i] = *(const bf16x8*)&sA[(wr + i * 16 + lr) * 64 + co];
#pragma unroll
        for (int j = 0; j < 4; ++j)
            bfr[j] = *(const bf16x8*)&sB[(wc + j * 16 + lr) * 64 + co];
#pragma unroll
        for (int i = 0; i < 4; ++i)
#pragma unroll
            for (int j = 0; j < 4; ++j)
                acc[i * 4 + j] = __builtin_amdgcn_mfma_f32_16x16x32_bf16(af[i], bfr[j], acc[i * 4 + j], 0, 0, 0);
    }
}

__device__ inline void kloop_pipe(const short* __restrict__ A, int lda,
                                  const short* __restrict__ B, int ldb, int Kd,
                                  f32x4* acc, short (*sm)[8192]) {
    const int tid = threadIdx.x, lane = tid & 63, wv = tid >> 6;
    const int quad = lane >> 4, lr = lane & 15;
    const int wr = (wv >> 1) * 64, wc = (wv & 1) * 64;
    const int NT = Kd >> 6;
    // prologue: tile 0 -> buf0, full drain
    stage_tile(A, lda, B, ldb, 0, sm[0], sm[1], tid);
    __builtin_amdgcn_sched_barrier(0);
    asm volatile("s_waitcnt vmcnt(0)" ::: "memory");
    __builtin_amdgcn_sched_barrier(0);
    __builtin_amdgcn_s_barrier();
    __builtin_amdgcn_sched_barrier(0);
    for (int t = 0; t < NT; ++t) {
        const int cur = (t & 1) << 1;                 // 0 or 2
        if (t + 1 < NT)                               // prefetch next tile into other buf
            stage_tile(A, lda, B, ldb, (t + 1) << 6, sm[cur ^ 2], sm[cur ^ 3], tid);
        __builtin_amdgcn_sched_barrier(0);
        compute_tile(sm[cur], sm[cur + 1], acc, wr, wc, lr, quad);
        __builtin_amdgcn_sched_barrier(0);
        asm volatile("s_waitcnt vmcnt(0)" ::: "memory");  // next tile landed (flew under MFMA)
        __builtin_amdgcn_sched_barrier(0);
        __builtin_amdgcn_s_barrier();                 // all waves done reading cur buf
        __builtin_amdgcn_sched_barrier(0);
    }
    // returns with all waves past final barrier, vmcnt drained -> safe to re-enter
}

__device__ inline void store_out(float* p, float v) { *p = v; }
__device__ inline void store_out(short* p, float v) { *p = f2bf(v); }

template <typename OutT>
__device__ inline void store_tile128(OutT* C, int ldc, const f32x4* acc) {
    const int lane = threadIdx.x & 63, wv = threadIdx.x >> 6;
    const int quad = lane >> 4, lr = lane & 15;
    const int wr = (wv >> 1) * 64, wc = (wv & 1) * 64;
#pragma unroll
    for (int i = 0; i < 4; ++i)
#pragma unroll
        for (int j = 0; j < 4; ++j)
#pragma unroll
            for (int r = 0; r < 4; ++r)
                store_out(&C[(size_t)(wr + i * 16 + quad * 4 + r) * ldc + wc + j * 16 + lr],
                          acc[i * 4 + j][r]);
}

// ---------------- unified projections ----------------
// grid 1536 blocks:
//   0..1023   : row-major Q|K: mt = bid>>3 (0..127), by = bid&7 (<4 -> Q cols, else K cols)
//               K blocks additionally scatter Kt[b][f][t] from registers.
//   1024..1535: Vt (feature-major): r = bid-1024 -> b = r&3, tt = (r>>2)&31, ft = r>>7
__global__ __launch_bounds__(256, 2) void proj_all(const short* __restrict__ Xb,
                                                   const short* __restrict__ W4T,
                                                   short* __restrict__ Qb, short* __restrict__ Kb,
                                                   short* __restrict__ Vt, short* __restrict__ Kt) {
    LDS_DECL;
    f32x4 acc[16];
#pragma unroll
    for (int i = 0; i < 16; ++i) acc[i] = (f32x4){0.f, 0.f, 0.f, 0.f};
    const int bid = blockIdx.x;
    const int lane = threadIdx.x & 63, wv = threadIdx.x >> 6;
    const int quad = lane >> 4, lr = lane & 15;
    const int wr = (wv >> 1) * 64, wc = (wv & 1) * 64;
    if (bid < 1024) {
        const int mt = bid >> 3, by = bid & 7;
        const short* At = Xb + (size_t)mt * 128 * 512;
        const short* Bt = W4T + (size_t)by * 128 * 512;   // by<4: Wq cols, else Wk cols
        short* Ct = ((by < 4) ? Qb : Kb) + (size_t)mt * 128 * 512 + (by & 3) * 128;
        kloop_pipe(At, 512, Bt, 512, 512, acc, sm);
        store_tile128(Ct, 512, acc);
        if (by >= 4) {
            // emit Kt[b][f][t] from registers (int2 scatter; block covers full
            // 128-t span per f, so L2 assembles complete lines -> no HBM overfetch)
            const int b = mt >> 5;
            const int t0b = (mt & 31) * 128;
            const int f0 = (by - 4) * 128;
#pragma unroll
            for (int i = 0; i < 4; ++i)
#pragma unroll
                for (int j = 0; j < 4; ++j) {
                    int f = f0 + wc + j * 16 + lr;
                    int tt0 = t0b + wr + i * 16 + quad * 4;
                    short tmp[4];
#pragma unroll
                    for (int r = 0; r < 4; ++r) tmp[r] = f2bf(acc[i * 4 + j][r]);
                    *(int2*)&Kt[((size_t)b * 512 + f) * 4096 + tt0] = *(const int2*)tmp;
                }
        }
    } else {
        const int r = bid - 1024;
        const int b = r & 3, tt = (r >> 2) & 31, ft = r >> 7;
        const short* At = W4T + (size_t)2 * 262144 + (size_t)ft * 128 * 512;   // Wv
        const short* Bt = Xb + ((size_t)b * 4096 + tt * 128) * 512;
        short* Ct = Vt + (size_t)b * 512 * 4096 + (size_t)ft * 128 * 4096 + tt * 128;
        kloop_pipe(At, 512, Bt, 512, 512, acc, sm);
        store_tile128(Ct, 4096, acc);
    }
}

// ---------------- chunked linear attention (C=256, 16 chunks/batch) ----------------

// AM[b,c][v][k] = sum_{t in chunk c} Vt[b][v][t] * Kt[b][k][t]; grid (4,4,64)
__global__ __launch_bounds__(256, 2) void phaseA(const short* __restrict__ Vt,
                                                 const short* __restrict__ Kt,
                                                 short* __restrict__ AM) {
    LDS_DECL;
    const int bc = blockIdx.z, b = bc >> 4, c = bc & 15;
    const short* Ap = Vt + ((size_t)b * 512 + blockIdx.x * 128) * 4096 + c * 256;
    const short* Bp = Kt + ((size_t)b * 512 + blockIdx.y * 128) * 4096 + c * 256;
    short* Cp = AM + (size_t)bc * 262144 + (size_t)blockIdx.x * 128 * 512 + blockIdx.y * 128;
    f32x4 acc[16];
#pragma unroll
    for (int i = 0; i < 16; ++i) acc[i] = (f32x4){0.f, 0.f, 0.f, 0.f};
    kloop_pipe(Ap, 4096, Bp, 4096, 256, acc, sm);
    store_tile128(Cp, 512, acc);
}

// merged: blocks 0..511 = exclusive prefix scan over chunks of AM (memory-bound);
//         blocks 512..767 = P = tril(Q_c K_c^T) (compute-bound) -- independent, overlap.
__global__ __launch_bounds__(256, 2) void scan_phaseS(short* __restrict__ AM,
                                                      const short* __restrict__ Q,
                                                      const short* __restrict__ K,
                                                      short* __restrict__ P) {
    LDS_DECL;
    if (blockIdx.x < 512) {
        int i = blockIdx.x * 256 + threadIdx.x;   // 0..131071
        int b = i >> 15;
        int vk8 = i & 32767;
        size_t base = (size_t)b * 16 * 262144 + (size_t)vk8 * 8;
        float acc[8];
#pragma unroll
        for (int s = 0; s < 8; ++s) acc[s] = 0.f;
        for (int c = 0; c < 16; ++c) {
            short* p = AM + base + (size_t)c * 262144;
            short in8[8];
            *(int4*)in8 = *(const int4*)p;
            short out8[8];
#pragma unroll
            for (int s = 0; s < 8; ++s) out8[s] = f2bf(acc[s]);
            *(int4*)p = *(const int4*)out8;
#pragma unroll
            for (int s = 0; s < 8; ++s) acc[s] += bf2f(in8[s]);
        }
        return;
    }
    const int e = blockIdx.x - 512;               // 0..255
    const int bc = e >> 2, mt = e & 1, nt = (e >> 1) & 1;
    if (mt < nt) return;                          // dead tile (never read)
    const int b = bc >> 4, c = bc & 15;
    short* Pt = P + (size_t)bc * 65536 + (size_t)mt * 128 * 256 + nt * 128;
    const short* Ap = Q + ((size_t)(b * 4096 + c * 256 + mt * 128)) * 512;
    const short* Bp = K + ((size_t)(b * 4096 + c * 256 + nt * 128)) * 512;
    f32x4 acc[16];
#pragma unroll
    for (int i = 0; i < 16; ++i) acc[i] = (f32x4){0.f, 0.f, 0.f, 0.f};
    kloop_pipe(Ap, 512, Bp, 512, 512, acc, sm);
    const int lane = threadIdx.x & 63, wv = threadIdx.x >> 6;
    const int quad = lane >> 4, lr = lane & 15;
    const int wr = (wv >> 1) * 64, wc = (wv & 1) * 64;
    const bool diag = (mt == nt);
#pragma unroll
    for (int i = 0; i < 4; ++i)
#pragma unroll
        for (int j = 0; j < 4; ++j)
#pragma unroll
            for (int r = 0; r < 4; ++r) {
                int t = wr + i * 16 + quad * 4 + r;
                int jj = wc + j * 16 + lr;
                float v = (!diag || jj <= t) ? acc[i * 4 + j][r] : 0.f;
                Pt[(size_t)t * 256 + jj] = f2bf(v);
            }
}

// Y_c = Q_c * Mpre_c^T + tril(P_c) * V_c ; grid (2 mt, 4 nt, 64 bc)
__global__ __launch_bounds__(256, 2) void phaseY(const short* __restrict__ Q,
                                                 const short* __restrict__ Mpre,
                                                 const short* __restrict__ P,
                                                 const short* __restrict__ Vt,
                                                 short* __restrict__ Y) {
    LDS_DECL;
    const int bc = blockIdx.z, b = bc >> 4, c = bc & 15;
    const int mt = blockIdx.x, nt = blockIdx.y;
    f32x4 acc[16];
#pragma unroll
    for (int i = 0; i < 16; ++i) acc[i] = (f32x4){0.f, 0.f, 0.f, 0.f};
    // inter: Y[t][v] += sum_k Q[t][k] * Mpre[v][k]
    const short* Ai = Q + ((size_t)(b * 4096 + c * 256 + mt * 128)) * 512;
    const short* Bi = Mpre + (size_t)bc * 262144 + (size_t)nt * 128 * 512;
    kloop_pipe(Ai, 512, Bi, 512, 512, acc, sm);
    // intra: Y[t][v] += sum_j P[t][j] * Vt[v][j]; for mt=0 only j<128 nonzero
    // (second call is safe: first call exits with vmcnt drained + all waves barriered)
    const short* Ap = P + (size_t)bc * 65536 + (size_t)mt * 128 * 256;
    const short* Bv = Vt + ((size_t)b * 512 + nt * 128) * 4096 + c * 256;
    kloop_pipe(Ap, 256, Bv, 4096, (mt + 1) * 128, acc, sm);
    short* Cp = Y + ((size_t)(b * 4096 + c * 256 + mt * 128)) * 512 + nt * 128;
    store_tile128(Cp, 512, acc);
}

// generic C[M,N] = A . Bt^T (output projection)
template <typename OutT>
__global__ __launch_bounds__(256, 2) void gemm128(const short* __restrict__ A, int lda,
                                                  const short* __restrict__ B, int ldb,
                                                  OutT* __restrict__ C, int ldc, int Kd) {
    LDS_DECL;
    const short* At = A + (size_t)blockIdx.x * 128 * lda;
    const short* Bt = B + (size_t)blockIdx.y * 128 * ldb;
    OutT* Ct = C + (size_t)blockIdx.x * 128 * ldc + blockIdx.y * 128;
    f32x4 acc[16];
#pragma unroll
    for (int i = 0; i < 16; ++i) acc[i] = (f32x4){0.f, 0.f, 0.f, 0.f};
    kloop_pipe(At, lda, Bt, ldb, Kd, acc, sm);
    store_tile128(Ct, ldc, acc);
}

// ---------------- host ----------------

extern "C" void kernel_launch(void* const* d_in, const int* in_sizes, int n_in,
                              void* d_out, int out_size, void* d_ws, size_t ws_size,
                              hipStream_t stream) {
    const float* x  = (const float*)d_in[0];
    const float* Wq = (const float*)d_in[1];
    const float* Wk = (const float*)d_in[2];
    const float* Wv = (const float*)d_in[3];
    const float* Wo = (const float*)d_in[4];
    float* out = (float*)d_out;

    const size_t NTD = 16384 * 512;   // 8,388,608 elems

    short* ws  = (short*)d_ws;
    short* Xb  = ws;                  // 8.39M
    short* Qb  = Xb + NTD;
    short* Kb  = Qb + NTD;
    short* Kt  = Kb + NTD;
    short* Vt  = Kt + NTD;
    short* P   = Vt + NTD;            // 4.19M
    short* W4T = P + 4194304;         // 1.05M : WqT|WkT|WvT|WoT
    short* AM  = W4T + 1048576;       // 16.78M
    short* Yb  = Kb;                  // Kb dead after scan_phaseS

    short* WoT = W4T + 3 * 262144;

    prep_kernel<<<12288, 256, 0, stream>>>(x, Xb, Wq, Wk, Wv, Wo, W4T);
    proj_all<<<1536, 256, 0, stream>>>(Xb, W4T, Qb, Kb, Vt, Kt);
    phaseA<<<dim3(4, 4, 64), 256, 0, stream>>>(Vt, Kt, AM);
    scan_phaseS<<<768, 256, 0, stream>>>(AM, Qb, Kb, P);
    phaseY<<<dim3(2, 4, 64), 256, 0, stream>>>(Qb, AM, P, Vt, Yb);
    gemm128<float><<<dim3(128, 4), 256, 0, stream>>>(Yb, 512, WoT, 512, out, 512, 512);
}